// Round 11
// baseline (130.047 us; speedup 1.0000x reference)
//
#include <hip/hip_runtime.h>
#include <hip/hip_bf16.h>

#define Bb 512
#define Tt 512
#define Kk 64
#define START_TAG 62
#define STOP_TAG 63
#define LN2F 0.69314718055994530942f
#define LOG2E 1.44269504088896340736f

typedef __attribute__((ext_vector_type(8))) short bf16x8;  // 8 bf16 in 4 VGPRs
typedef __attribute__((ext_vector_type(4))) float f32x4;   // MFMA C/D

__device__ inline short f2bf(float x) {
    __hip_bfloat16 h = __float2bfloat16(x);
    short s; __builtin_memcpy(&s, &h, 2); return s;
}
// pack 2 f32 -> 2 bf16 in one instruction
__device__ inline unsigned cvtpk(float lo, float hi) {
    unsigned r;
    asm("v_cvt_pk_bf16_f32 %0, %1, %2" : "=v"(r) : "v"(lo), "v"(hi));
    return r;
}
__device__ inline float bperm(int addr_bytes, float v) {
    return __int_as_float(__builtin_amdgcn_ds_bpermute(addr_bytes, __float_as_int(v)));
}

// One sequence per 64-lane wave; alpha recursion as MFMA matvec in exp-space.
// Layout (HW-verified r4-r10, absmax 0.0): tag tau(c,r)=32c+16*(r>=4)+4g+(r&3)
// on both A and B sides; D tile i reg r = tag 16i+4g+r -> D feeds next B with
// register moves only.
// Round-11: NO addressed LDS in the loop. r8/r9/r10 localized the ~350
// stall-cyc/step to the LDS F-path (dynamic/aliasable ds_read/ds_write force
// conservative lgkmcnt waits; r9 disproved the MFMA-latency theory). F is now
// delivered by 16 ds_bpermute per step -- register-exact dependencies, no
// barriers -- issued ONE ITERATION ahead of consumption (r4's bpermute was
// on-chain; this one is fully decoupled). Emit ring 6 deep (loads ~3
// iterations ahead). Rescale queue shortened for the 2-step produce->consume
// distance: in-flight = {kemb}; knew = exponent(probe) - kemb (r7 principle).
__global__ __launch_bounds__(64, 1) void crf_forward_mfma(
    const float* __restrict__ feats,        // (B,T,K)
    const float* __restrict__ transitions,  // (K,K), trans[i,j] = score j->i
    const int* __restrict__ lengths,        // (B,)
    float* __restrict__ fwd_out)            // (B,)
{
    const int b   = blockIdx.x;
    const int l   = threadIdx.x;
    const int row = l & 15;   // A row / D col
    const int g   = l >> 4;   // k-group

    // A fragments: A[i][c] slot r = exp(trans[16i+row][tau(c,r)])
    bf16x8 A00, A01, A10, A11, A20, A21, A30, A31, S0, S1;
#define MKA(Av, i, c) {                                                       \
    const float* p = transitions + (16*(i)+row)*Kk + 32*(c) + 4*g;            \
    float4 lo = *(const float4*)p; float4 hi = *(const float4*)(p + 16);      \
    Av[0]=f2bf(__expf(lo.x)); Av[1]=f2bf(__expf(lo.y));                       \
    Av[2]=f2bf(__expf(lo.z)); Av[3]=f2bf(__expf(lo.w));                       \
    Av[4]=f2bf(__expf(hi.x)); Av[5]=f2bf(__expf(hi.y));                       \
    Av[6]=f2bf(__expf(hi.z)); Av[7]=f2bf(__expf(hi.w)); }
    MKA(A00,0,0) MKA(A01,0,1) MKA(A10,1,0) MKA(A11,1,1)
    MKA(A20,2,0) MKA(A21,2,1) MKA(A30,3,0) MKA(A31,3,1)
#undef MKA
    // Terminal fragments: row 0 = exp(trans[STOP][tau]), rows 1..15 = 0
#define MKS(Av, c) {                                                          \
    const float* p = transitions + STOP_TAG*Kk + 32*(c) + 4*g;                \
    float4 lo = *(const float4*)p; float4 hi = *(const float4*)(p + 16);      \
    const bool z = (row == 0);                                                \
    Av[0]=z?f2bf(__expf(lo.x)):(short)0; Av[1]=z?f2bf(__expf(lo.y)):(short)0; \
    Av[2]=z?f2bf(__expf(lo.z)):(short)0; Av[3]=z?f2bf(__expf(lo.w)):(short)0; \
    Av[4]=z?f2bf(__expf(hi.x)):(short)0; Av[5]=z?f2bf(__expf(hi.y)):(short)0; \
    Av[6]=z?f2bf(__expf(hi.z)):(short)0; Av[7]=z?f2bf(__expf(hi.w)):(short)0; }
    MKS(S0,0) MKS(S1,1)
#undef MKS

    const int len = lengths[b];
    const float* fb = feats + (size_t)b * Tt * Kk + l;  // natural: lane = tag

    // alpha0: 1 at START=62 -> B1 slot 6, g=3
    bf16x8 B0 = {}; bf16x8 B1 = {};
    if (g == 3) B1[6] = (short)0x3F80;  // bf16(1.0)

    const int vb = g << 4;  // bpermute byte base (src lane 4g -> byte 16g)

    // ---- prologue: FA = F(0), FB = F(1) via exp2 + bpermute ----
    float FA[16], FB[16], NFA[16], NFB[16];
    {
        const float f0 = __builtin_amdgcn_exp2f(fb[0]  * LOG2E);
        const float f1 = __builtin_amdgcn_exp2f(fb[Kk] * LOG2E);
#define BPALL(DST, SRC)                                                       \
        DST[0]=bperm(vb+0,SRC);    DST[1]=bperm(vb+4,SRC);                    \
        DST[2]=bperm(vb+8,SRC);    DST[3]=bperm(vb+12,SRC);                   \
        DST[4]=bperm(vb+64,SRC);   DST[5]=bperm(vb+68,SRC);                   \
        DST[6]=bperm(vb+72,SRC);   DST[7]=bperm(vb+76,SRC);                   \
        DST[8]=bperm(vb+128,SRC);  DST[9]=bperm(vb+132,SRC);                  \
        DST[10]=bperm(vb+136,SRC); DST[11]=bperm(vb+140,SRC);                 \
        DST[12]=bperm(vb+192,SRC); DST[13]=bperm(vb+196,SRC);                 \
        DST[14]=bperm(vb+200,SRC); DST[15]=bperm(vb+204,SRC);
        BPALL(FA, f0)
        BPALL(FB, f1)
    }

    // emit ring, 6 deep: er0..er5 = rows t+2..t+7 (rows always allocated)
    float er0 = fb[2 * Kk], er1 = fb[3 * Kk], er2 = fb[4 * Kk];
    float er3 = fb[5 * Kk], er4 = fb[6 * Kk], er5 = fb[7 * Kk];

    const f32x4 zz = {0.f, 0.f, 0.f, 0.f};
    int ktot = 0;
    int kq = 0, kemb = 0;   // kq: k in F(t) (consumed this iter); kemb: in F(t+2)
    float probeA, probeB;

#define MFMA16(Aa, Bx, Cc) __builtin_amdgcn_mfma_f32_16x16x32_bf16(Aa, Bx, Cc, 0, 0, 0)

    // chained pairs (r8-best) + scalar F multiply (constant-indexed regs)
#define STEP(FF, PR) {                                                        \
    f32x4 d0 = MFMA16(A00, B0, zz); d0 = MFMA16(A01, B1, d0);                 \
    f32x4 d1 = MFMA16(A10, B0, zz); d1 = MFMA16(A11, B1, d1);                 \
    f32x4 d2 = MFMA16(A20, B0, zz); d2 = MFMA16(A21, B1, d2);                 \
    f32x4 d3 = MFMA16(A30, B0, zz); d3 = MFMA16(A31, B1, d3);                 \
    const float m00 = d0[0]*FF[0],  m01 = d0[1]*FF[1];                        \
    const float m02 = d0[2]*FF[2],  m03 = d0[3]*FF[3];                        \
    const float m10 = d1[0]*FF[4],  m11 = d1[1]*FF[5];                        \
    const float m12 = d1[2]*FF[6],  m13 = d1[3]*FF[7];                        \
    const float m20 = d2[0]*FF[8],  m21 = d2[1]*FF[9];                        \
    const float m22 = d2[2]*FF[10], m23 = d2[3]*FF[11];                       \
    const float m30 = d3[0]*FF[12], m31 = d3[1]*FF[13];                       \
    const float m32 = d3[2]*FF[14], m33 = d3[3]*FF[15];                       \
    PR = m00;                                                                 \
    union { unsigned u[4]; bf16x8 v; } nb0, nb1;                              \
    nb0.u[0] = cvtpk(m00, m01); nb0.u[1] = cvtpk(m02, m03);                   \
    nb0.u[2] = cvtpk(m10, m11); nb0.u[3] = cvtpk(m12, m13);                   \
    nb1.u[0] = cvtpk(m20, m21); nb1.u[1] = cvtpk(m22, m23);                   \
    nb1.u[2] = cvtpk(m30, m31); nb1.u[3] = cvtpk(m32, m33);                   \
    B0 = nb0.v; B1 = nb1.v; }

    int t = 0;
    for (; t + 1 < len; t += 2) {
        // produce F(t+2), F(t+3): exp2 from emit ring, deliver via bpermute.
        // Register-only deps; consumed NEXT iteration (~1 iter of slack).
        const float frA2 = __builtin_amdgcn_exp2f(fmaf(er0, LOG2E, -(float)kemb));
        const float frB2 = __builtin_amdgcn_exp2f(er1 * LOG2E);
        BPALL(NFA, frA2)
        BPALL(NFB, frB2)

        STEP(FA, probeA)
        STEP(FB, probeB)

        // ---- bookkeeping (off the MFMA chain) ----
        ktot += kq;   // k embedded in F(t), consumed by STEP A above
        const unsigned pb =
            (unsigned)__builtin_amdgcn_readfirstlane(__float_as_int(probeB));
        // probeB scale reflects corrections through F(t); in flight: kemb (F(t+2))
        int knew = ((int)((pb >> 23) & 255) - 127) - kemb;
        knew = (knew > 100) ? 100 : ((knew < -100) ? -100 : knew);
        kq = kemb; kemb = knew;
#pragma unroll
        for (int q = 0; q < 16; ++q) { FA[q] = NFA[q]; FB[q] = NFB[q]; }
        er0 = er2; er1 = er3; er2 = er4; er3 = er5;
        const int r0 = (t + 8 < Tt) ? t + 8 : Tt - 1;
        const int r1 = (t + 9 < Tt) ? t + 9 : Tt - 1;
        er4 = fb[r0 * Kk]; er5 = fb[r1 * Kk];
        (void)probeA;
    }

    // tail (len odd): one step with FA = F(t)
    if (t < len) {
        STEP(FA, probeA)
        ktot += kq;
        (void)probeA;
    }

    // terminal: d4 row0 = etstop . alpha (current scale 2^-ktot)
    f32x4 d4 = MFMA16(S0, B0, zz); d4 = MFMA16(S1, B1, d4);
    const float term = __uint_as_float(
        (unsigned)__builtin_amdgcn_readfirstlane(__float_as_int(d4[0])));
    if (l == 0) fwd_out[b] = (float)ktot * LN2F + logf(term);
#undef STEP
#undef MFMA16
#undef BPALL
}

// Gold path score: fully parallel over t (lane-strided).
__global__ __launch_bounds__(64) void crf_gold_kernel(
    const float* __restrict__ feats,
    const float* __restrict__ transitions,
    const int* __restrict__ tags,     // (B,T)
    const int* __restrict__ lengths,  // (B,)
    float* __restrict__ gold_out)     // (B,)
{
    const int b = blockIdx.x;
    const int lane = threadIdx.x;
    const int len = lengths[b];
    const int* tb = tags + b * Tt;
    const float* fb = feats + (size_t)b * Tt * Kk;

    float acc = 0.f;
    for (int t = lane; t < len; t += 64) {
        const int tg = tb[t];
        const int prev = (t == 0) ? START_TAG : tb[t - 1];
        acc += transitions[tg * Kk + prev];  // score prev -> tg
        acc += fb[t * Kk + tg];              // emission
    }
    if (lane == 0) acc += transitions[STOP_TAG * Kk + tb[len - 1]];  // last -> STOP
#pragma unroll
    for (int off = 32; off >= 1; off >>= 1) acc += __shfl_xor(acc, off, 64);
    if (lane == 0) gold_out[b] = acc;
}

__global__ __launch_bounds__(512) void crf_reduce_kernel(
    const float* __restrict__ fwd, const float* __restrict__ gold,
    float* __restrict__ out)
{
    const int i = threadIdx.x;  // 0..511
    float v = fwd[i] - gold[i];
#pragma unroll
    for (int off = 32; off >= 1; off >>= 1) v += __shfl_xor(v, off, 64);
    __shared__ float ws[8];
    if ((i & 63) == 0) ws[i >> 6] = v;
    __syncthreads();
    if (i < 8) {
        float s = ws[i];
#pragma unroll
        for (int off = 4; off >= 1; off >>= 1) s += __shfl_xor(s, off, 8);
        if (i == 0) out[0] = s * (1.0f / (float)Bb);
    }
}

extern "C" void kernel_launch(void* const* d_in, const int* in_sizes, int n_in,
                              void* d_out, int out_size, void* d_ws, size_t ws_size,
                              hipStream_t stream) {
    const float* feats = (const float*)d_in[0];
    const float* trans = (const float*)d_in[1];
    const int* tags = (const int*)d_in[2];
    const int* lengths = (const int*)d_in[3];
    float* out = (float*)d_out;
    float* fwd = (float*)d_ws;
    float* gold = fwd + Bb;

    crf_gold_kernel<<<Bb, 64, 0, stream>>>(feats, trans, tags, lengths, gold);
    crf_forward_mfma<<<Bb, 64, 0, stream>>>(feats, trans, lengths, fwd);
    crf_reduce_kernel<<<1, 512, 0, stream>>>(fwd, gold, out);
}